// Round 5
// baseline (224.932 us; speedup 1.0000x reference)
//
#include <hip/hip_runtime.h>
#include <hip/hip_bf16.h>
#include <stdint.h>

#define B_ 4
#define T_ 2048
#define C_ 1024
#define H_ 16
#define D_ 64

typedef short bf16x8 __attribute__((ext_vector_type(8)));
typedef short bf16x4 __attribute__((ext_vector_type(4)));
typedef float f32x4 __attribute__((ext_vector_type(4)));
typedef unsigned short u16;

#define HAS_M16 __has_builtin(__builtin_amdgcn_mfma_f32_16x16x16bf16_1k)

// log2(e)/sqrt(D): folded into Q at the qkv epilogue -> scores in exp2 domain.
#define QSCALE 0.18033688011112042f

__device__ __forceinline__ u16 f2bf(float f) {
    __hip_bfloat16 h = __float2bfloat16(f);
    return *reinterpret_cast<u16*>(&h);
}

__device__ __forceinline__ float fexp2(float x) {
    float r;
    asm("v_exp_f32 %0, %1" : "=v"(r) : "v"(x));
    return r;
}

__device__ __forceinline__ void gload16(const void* g, void* l) {
    __builtin_amdgcn_global_load_lds(
        (const __attribute__((address_space(1))) unsigned int*)g,
        (__attribute__((address_space(3))) unsigned int*)l, 16, 0, 0);
}

// ---------------- cast fp32 -> bf16 (same layout) ----------------
__global__ void k_cast_bf16(const float* __restrict__ src, u16* __restrict__ dst, int n) {
    int i = (blockIdx.x * blockDim.x + threadIdx.x) * 4;
    if (i >= n) return;
    float4 f = *reinterpret_cast<const float4*>(src + i);
    ushort4 o;
    o.x = f2bf(f.x); o.y = f2bf(f.y); o.z = f2bf(f.z); o.w = f2bf(f.w);
    *reinterpret_cast<ushort4*>(dst + i) = o;
}

// ---------------- transpose + cast: [R][Cc] f32 -> [Cc][R] bf16 ----------------
__global__ void k_transpose_bf16(const float* __restrict__ src, u16* __restrict__ dst,
                                 int R, int Cc) {
    __shared__ float tile[32][33];
    int c0 = blockIdx.x * 32, r0 = blockIdx.y * 32;
    int tx = threadIdx.x, ty = threadIdx.y;
#pragma unroll
    for (int i = 0; i < 4; i++)
        tile[ty + i * 8][tx] = src[(size_t)(r0 + ty + i * 8) * Cc + c0 + tx];
    __syncthreads();
#pragma unroll
    for (int i = 0; i < 4; i++)
        dst[(size_t)(c0 + ty + i * 8) * R + r0 + tx] = f2bf(tile[tx][ty + i * 8]);
}

// ---------------- 8-phase GEMM: C[M,N] = A[M,K] * Bt[N,K]^T + bias ----------------
// BM=128 BN=256 BK=64, 8 waves (2M x 4N), per-wave 64x64 out.
// 2-dbuf LDS (96 KB), XOR chunk-swizzle (inverse on global source).
// Per iteration = 2 K-tiles = 8 phases; one 16KB stage unit per phase;
// vmcnt(4) only at phases 3 and 7 (counted, never 0 mid-loop).
// Stage ring (iteration-local):
//   ph0: A1<-t1   ph1: B0a<-t0+2  ph2: B0b<-t0+2  ph3: vmcnt(4)
//   ph4: A0<-t0+2 ph5: B1a<-t1+2  ph6: B1b<-t1+2  ph7: vmcnt(4)
// WAR: every stage lands >=1 full phase (2 barriers) after its unit's last read.
// RAW: each unit's loads complete >=1 vmcnt(4) checkpoint before its first read.
template <int EPI>
__launch_bounds__(512, 2)
__global__ void k_gemm8(const u16* __restrict__ A, const u16* __restrict__ Bt,
                        const float* __restrict__ bias, int N,
                        float* __restrict__ outf,
                        u16* __restrict__ qw, u16* __restrict__ kw, u16* __restrict__ vw) {
    constexpr int K = 1024, NK = 16, ITERS = NK / 2;
    __shared__ u16 Asl[2][128 * 64];   // 2 x 16 KB
    __shared__ u16 Bsl[2][256 * 64];   // 2 x 32 KB
    const int tid = threadIdx.x;
    const int lane = tid & 63, w = tid >> 6;
    const int lr = lane & 15, lg = lane >> 4;
    const int nwg = 64 * (N >> 8);
    const int cpx = nwg >> 3;
    const int swzb = (blockIdx.x & 7) * cpx + (blockIdx.x >> 3);  // bijective (nwg%8==0)
    const int m0 = (swzb & 63) * 128;
    const int n0 = (swzb >> 6) * 256;
    const int wm = (w >> 2) * 64, wn = (w & 3) * 64;
    const int xswz = (lr & 7) << 4;

    const u16* Abase = A + (size_t)m0 * K;
    const u16* Bbase = Bt + (size_t)n0 * K;

    // stage one 16KB unit (128 rows x 64 cols bf16), source pre-inverse-swizzled
    auto stageU = [&](u16* lunit, const u16* g) {
#pragma unroll
        for (int i = 0; i < 2; i++) {
            int idx = i * 512 + tid;
            int row = idx >> 3, ch = idx & 7, gch = ch ^ (row & 7);
            gload16(g + (size_t)row * K + gch * 8, (char*)lunit + i * 8192 + w * 1024);
        }
    };

    f32x4 acc[4][4];
#pragma unroll
    for (int i = 0; i < 4; i++)
#pragma unroll
        for (int j = 0; j < 4; j++) acc[i][j] = (f32x4){0.f, 0.f, 0.f, 0.f};

    // prologue: dbuf0 <- K-tile 0 (A0,B0a,B0b); B1a,B1b <- K-tile 1
    stageU(Asl[0], Abase);
    stageU(Bsl[0], Bbase);
    stageU(Bsl[0] + 128 * 64, Bbase + (size_t)128 * K);
    stageU(Bsl[1], Bbase + 64);
    stageU(Bsl[1] + 128 * 64, Bbase + (size_t)128 * K + 64);
    asm volatile("s_waitcnt vmcnt(4)" ::: "memory");
    __builtin_amdgcn_s_barrier();

    bf16x8 bfr[4][2];
    for (int it = 0; it < ITERS; ++it) {
        const int t1 = 2 * it + 1;
        const int t0n = (2 * it + 2 < NK) ? 2 * it + 2 : NK - 1;  // clamped: dead at last iter
        const int t1n = (2 * it + 3 < NK) ? 2 * it + 3 : NK - 1;
        const bool last = (it == ITERS - 1);

#pragma unroll
        for (int half = 0; half < 2; ++half) {   // half 0: dbuf0/t0, half 1: dbuf1/t1
            const char* Ab = (const char*)Asl[half];
            const char* Bb = (const char*)Bsl[half];
#pragma unroll
            for (int p = 0; p < 4; ++p) {
                // --- ds_reads for this phase ---
                bf16x8 af[2];
                int arow = wm + p * 16 + lr;
#pragma unroll
                for (int kk = 0; kk < 2; kk++)
                    af[kk] = *reinterpret_cast<const bf16x8*>(
                        Ab + arow * 128 + ((kk * 64 + lg * 16) ^ xswz));
                if (p == 0) {
#pragma unroll
                    for (int nf = 0; nf < 4; nf++) {
                        int brow = wn + nf * 16 + lr;
#pragma unroll
                        for (int kk = 0; kk < 2; kk++)
                            bfr[nf][kk] = *reinterpret_cast<const bf16x8*>(
                                Bb + brow * 128 + ((kk * 64 + lg * 16) ^ xswz));
                    }
                }
                // --- stage / vmcnt per ring schedule ---
                if (half == 0) {
                    if (p == 0)      stageU(Asl[1], Abase + t1 * 64);
                    else if (p == 1) stageU(Bsl[0], Bbase + t0n * 64);
                    else if (p == 2) stageU(Bsl[0] + 128 * 64, Bbase + (size_t)128 * K + t0n * 64);
                    else {
                        if (!last) asm volatile("s_waitcnt vmcnt(4)" ::: "memory");
                        else       asm volatile("s_waitcnt vmcnt(0)" ::: "memory");
                    }
                } else {
                    if (p == 0)      stageU(Asl[0], Abase + t0n * 64);
                    else if (p == 1) stageU(Bsl[1], Bbase + t1n * 64);
                    else if (p == 2) stageU(Bsl[1] + 128 * 64, Bbase + (size_t)128 * K + t1n * 64);
                    else             asm volatile("s_waitcnt vmcnt(4)" ::: "memory");
                }
                __builtin_amdgcn_s_barrier();
                __builtin_amdgcn_s_setprio(1);
#pragma unroll
                for (int nf = 0; nf < 4; nf++)
#pragma unroll
                    for (int kk = 0; kk < 2; kk++)
                        acc[p][nf] = __builtin_amdgcn_mfma_f32_16x16x32_bf16(
                            af[kk], bfr[nf][kk], acc[p][nf], 0, 0, 0);
                __builtin_amdgcn_s_setprio(0);
                __builtin_amdgcn_s_barrier();
            }
        }
    }

    if (EPI == 0) {
#pragma unroll
        for (int mf = 0; mf < 4; ++mf)
#pragma unroll
            for (int nf = 0; nf < 4; ++nf) {
                int ng = n0 + wn + nf * 16 + lr;
                float bs = bias[ng];
#pragma unroll
                for (int r = 0; r < 4; ++r) {
                    int mg = m0 + wm + mf * 16 + lg * 4 + r;
                    outf[(size_t)mg * N + ng] = acc[mf][nf][r] + bs;
                }
            }
    } else {
        const int sec = n0 >> 10;  // 0:q 1:k 2:v — uniform per block (1024%256==0)
        const float sc = (sec == 0) ? QSCALE : 1.0f;
#pragma unroll
        for (int mf = 0; mf < 4; ++mf)
#pragma unroll
            for (int nf = 0; nf < 4; ++nf) {
                int ng = n0 + wn + nf * 16 + lr;
                float bs = bias[ng];
                int hd = ng & 1023;
                int h = hd >> 6, d = hd & 63;
                int mgb = m0 + wm + mf * 16 + lg * 4;
                int b = mgb >> 11, t0v = mgb & 2047;
                if (sec == 2) {
                    ushort4 pk;
                    pk.x = f2bf(acc[mf][nf][0] + bs);
                    pk.y = f2bf(acc[mf][nf][1] + bs);
                    pk.z = f2bf(acc[mf][nf][2] + bs);
                    pk.w = f2bf(acc[mf][nf][3] + bs);
                    *reinterpret_cast<ushort4*>(&vw[((size_t)(b * H_ + h) * D_ + d) * T_ + t0v]) = pk;
                } else {
                    u16* dst = (sec == 0) ? qw : kw;
#pragma unroll
                    for (int r = 0; r < 4; ++r)
                        dst[((size_t)(b * H_ + h) * T_ + t0v + r) * D_ + d] = f2bf((acc[mf][nf][r] + bs) * sc);
                }
            }
    }
}

// ---------------- flash attention (unchanged from round 4) ----------------
#if HAS_M16
__launch_bounds__(256, 4)
#else
__launch_bounds__(256, 3)
#endif
__global__ void k_attn(const u16* __restrict__ qw, const u16* __restrict__ kw,
                       const u16* __restrict__ vw, u16* __restrict__ attn) {
    __shared__ u16 Ks[2][64][64];
    __shared__ u16 Vs[2][64][64];
#if !HAS_M16
    __shared__ u16 pshm[4][32][64];
#endif
    const int tid = threadIdx.x, lane = tid & 63, w = tid >> 6;
    const int lr = lane & 15, lg = lane >> 4;
    const int bid = blockIdx.x;
    const int logical = (bid & 7) * 128 + (bid >> 3);
    const int bh = logical >> 4, qb = logical & 15;
    const int b = bh >> 4, h = bh & 15;
    const int q0 = qb * 128 + w * 32;
    const u16* qbase = qw + (size_t)bh * T_ * D_;
    const u16* kbase = kw + (size_t)bh * T_ * D_;
    const u16* vbase = vw + (size_t)bh * D_ * T_;

    bf16x8 qf[2][2];
#pragma unroll
    for (int jq = 0; jq < 2; jq++)
#pragma unroll
        for (int kd = 0; kd < 2; kd++)
            qf[jq][kd] = *reinterpret_cast<const bf16x8*>(
                &qbase[(size_t)(q0 + jq * 16 + lr) * D_ + kd * 32 + lg * 8]);

    auto stageK = [&](int kt, int buf) {
#pragma unroll
        for (int i = 0; i < 2; i++) {
            int idx = i * 256 + tid;
            int row = idx >> 3, ch = idx & 7;
            int gch = ch ^ (row & 7);
            gload16(kbase + ((size_t)(kt * 64 + row) * 64 + gch * 8),
                    (char*)&Ks[buf][0][0] + i * 4096 + w * 1024);
        }
    };
    auto stageV = [&](int kt, int buf) {
#pragma unroll
        for (int i = 0; i < 2; i++) {
            int idx = i * 256 + tid;
            int row = idx >> 3, ch = idx & 7;
            int gch = ch ^ (row & 7);
            gload16(vbase + ((size_t)row * T_ + kt * 64 + gch * 8),
                    (char*)&Vs[buf][0][0] + i * 4096 + w * 1024);
        }
    };

    f32x4 o[4][2];
#pragma unroll
    for (int md = 0; md < 4; md++)
#pragma unroll
        for (int jq = 0; jq < 2; jq++) o[md][jq] = (f32x4){0.f, 0.f, 0.f, 0.f};
    float l_run[2] = {0.f, 0.f};

    const int NT = T_ / 64;
    stageK(0, 0);
    stageV(0, 0);

    for (int kt = 0; kt < NT; ++kt) {
        const int cur = kt & 1;
        if (kt + 1 < NT) {
            stageK(kt + 1, cur ^ 1);
            stageV(kt + 1, cur ^ 1);
            asm volatile("s_waitcnt vmcnt(4)" ::: "memory");
        } else {
            asm volatile("s_waitcnt vmcnt(0)" ::: "memory");
        }
        __builtin_amdgcn_s_barrier();

        bf16x8 ka[4][2];
#pragma unroll
        for (int mk = 0; mk < 4; mk++)
#pragma unroll
            for (int kd = 0; kd < 2; kd++) {
                int row = mk * 16 + lr;
                int colb = (kd * 64 + lg * 16) ^ ((row & 7) << 4);
                ka[mk][kd] = *reinterpret_cast<const bf16x8*>(
                    (const char*)&Ks[cur][0][0] + row * 128 + colb);
            }

        f32x4 s[4][2];
#pragma unroll
        for (int mk = 0; mk < 4; mk++)
#pragma unroll
            for (int jq = 0; jq < 2; jq++) s[mk][jq] = (f32x4){0.f, 0.f, 0.f, 0.f};
        __builtin_amdgcn_s_setprio(1);
#pragma unroll
        for (int kd = 0; kd < 2; kd++)
#pragma unroll
            for (int mk = 0; mk < 4; mk++)
#pragma unroll
                for (int jq = 0; jq < 2; jq++)
                    s[mk][jq] = __builtin_amdgcn_mfma_f32_16x16x32_bf16(ka[mk][kd], qf[jq][kd], s[mk][jq], 0, 0, 0);
        __builtin_amdgcn_s_setprio(0);

#if HAS_M16
        bf16x4 pfrag[2][4];
#endif
#pragma unroll
        for (int jq = 0; jq < 2; jq++) {
            float psum = 0.f;
#pragma unroll
            for (int mk = 0; mk < 4; mk++) {
                float p0 = fexp2(s[mk][jq][0]);
                float p1 = fexp2(s[mk][jq][1]);
                float p2 = fexp2(s[mk][jq][2]);
                float p3 = fexp2(s[mk][jq][3]);
                psum += (p0 + p1) + (p2 + p3);
#if HAS_M16
                pfrag[jq][mk] = (bf16x4){(short)f2bf(p0), (short)f2bf(p1),
                                         (short)f2bf(p2), (short)f2bf(p3)};
#else
                ushort4 pk;
                pk.x = f2bf(p0); pk.y = f2bf(p1); pk.z = f2bf(p2); pk.w = f2bf(p3);
                int prow = jq * 16 + lr;
                int pcolb = (mk * 32 + lg * 8) ^ ((prow & 7) << 4);
                *reinterpret_cast<ushort4*>((char*)&pshm[w][0][0] + prow * 128 + pcolb) = pk;
#endif
            }
            l_run[jq] += psum;
        }

#if HAS_M16
        __builtin_amdgcn_s_setprio(1);
#pragma unroll
        for (int md = 0; md < 4; md++) {
            int row = md * 16 + lr;
#pragma unroll
            for (int mk = 0; mk < 4; mk++) {
                int colb = (mk * 32 + lg * 8) ^ ((row & 7) << 4);
                bf16x4 va = *reinterpret_cast<const bf16x4*>(
                    (const char*)&Vs[cur][0][0] + row * 128 + colb);
                o[md][0] = __builtin_amdgcn_mfma_f32_16x16x16bf16_1k(va, pfrag[0][mk], o[md][0], 0, 0, 0);
                o[md][1] = __builtin_amdgcn_mfma_f32_16x16x16bf16_1k(va, pfrag[1][mk], o[md][1], 0, 0, 0);
            }
        }
        __builtin_amdgcn_s_setprio(0);
#else
        asm volatile("s_waitcnt lgkmcnt(0)" ::: "memory");
        bf16x8 pb[2][2];
#pragma unroll
        for (int jq = 0; jq < 2; jq++)
#pragma unroll
            for (int kk = 0; kk < 2; kk++) {
                int prow = jq * 16 + lr;
                int pcolb = (kk * 64 + lg * 16) ^ ((prow & 7) << 4);
                pb[jq][kk] = *reinterpret_cast<const bf16x8*>(
                    (const char*)&pshm[w][0][0] + prow * 128 + pcolb);
            }
        bf16x8 va[4][2];
#pragma unroll
        for (int md = 0; md < 4; md++)
#pragma unroll
            for (int kk = 0; kk < 2; kk++) {
                int row = md * 16 + lr;
                int colb = (kk * 64 + lg * 16) ^ ((row & 7) << 4);
                va[md][kk] = *reinterpret_cast<const bf16x8*>(
                    (const char*)&Vs[cur][0][0] + row * 128 + colb);
            }
        __builtin_amdgcn_s_setprio(1);
#pragma unroll
        for (int md = 0; md < 4; md++)
#pragma unroll
            for (int jq = 0; jq < 2; jq++)
#pragma unroll
                for (int kk = 0; kk < 2; kk++)
                    o[md][jq] = __builtin_amdgcn_mfma_f32_16x16x32_bf16(va[md][kk], pb[jq][kk], o[md][jq], 0, 0, 0);
        __builtin_amdgcn_s_setprio(0);
#endif

        __builtin_amdgcn_s_barrier();
    }

#pragma unroll
    for (int jq = 0; jq < 2; jq++) {
        float l = l_run[jq];
        l += __shfl_xor(l, 16);
        l += __shfl_xor(l, 32);
        float rinv = 1.f / l;
        int q = q0 + jq * 16 + lr;
#pragma unroll
        for (int md = 0; md < 4; md++) {
            int d0 = md * 16 + lg * 4;
            ushort4 pk;
            pk.x = f2bf(o[md][jq][0] * rinv);
            pk.y = f2bf(o[md][jq][1] * rinv);
            pk.z = f2bf(o[md][jq][2] * rinv);
            pk.w = f2bf(o[md][jq][3] * rinv);
            *reinterpret_cast<ushort4*>(&attn[((size_t)(b * T_ + q)) * C_ + h * D_ + d0]) = pk;
        }
    }
}

extern "C" void kernel_launch(void* const* d_in, const int* in_sizes, int n_in,
                              void* d_out, int out_size, void* d_ws, size_t ws_size,
                              hipStream_t stream) {
    const float* y = (const float*)d_in[0];
    const float* W_attn = (const float*)d_in[1];
    const float* b_attn = (const float*)d_in[2];
    const float* W_proj = (const float*)d_in[3];
    const float* b_proj = (const float*)d_in[4];

    char* ws = (char*)d_ws;
    u16* y_bf = (u16*)(ws);                                // 16 MB
    u16* WaT  = (u16*)(ws + 16777216);                     // 6 MB  [3072][1024]
    u16* WpT  = (u16*)(ws + 16777216 + 6291456);           // 2 MB  [1024][1024]
    u16* q_ws = (u16*)(ws + 25165824);                     // 16 MB [B,H,T,D] (prescaled)
    u16* k_ws = (u16*)(ws + 25165824 + 16777216);          // 16 MB [B,H,T,D]
    u16* v_ws = (u16*)(ws + 25165824 + 33554432);          // 16 MB [B,H,D,T]
    u16* attn = (u16*)(ws + 25165824 + 50331648);          // 16 MB [B,T,C]

    k_cast_bf16<<<8192, 256, 0, stream>>>(y, y_bf, B_ * T_ * C_);
    k_transpose_bf16<<<dim3(96, 32), dim3(32, 8), 0, stream>>>(W_attn, WaT, 1024, 3072);
    k_transpose_bf16<<<dim3(32, 32), dim3(32, 8), 0, stream>>>(W_proj, WpT, 1024, 1024);
    k_gemm8<1><<<768, 512, 0, stream>>>(y_bf, WaT, b_attn, 3072,
                                        nullptr, q_ws, k_ws, v_ws);
    k_attn<<<1024, 256, 0, stream>>>(q_ws, k_ws, v_ws, attn);
    k_gemm8<0><<<256, 512, 0, stream>>>(attn, WpT, b_proj, 1024,
                                        (float*)d_out, nullptr, nullptr, nullptr);
}